// Round 4
// baseline (750.949 us; speedup 1.0000x reference)
//
#include <hip/hip_runtime.h>
#include <hip/hip_fp16.h>

#define NB 256      // batch
#define NT 1024     // time
#define ND 64       // input dim
#define NH 128      // hidden dim

typedef __fp16 half8 __attribute__((ext_vector_type(8)));
typedef float float4v __attribute__((ext_vector_type(4)));

static __device__ __forceinline__ float fast_tanh(float v) {
    float e = __expf(2.0f * v);
    return 1.0f - 2.0f * __builtin_amdgcn_rcpf(e + 1.0f);
}

// One wave per batch. Recurrence matvec y = W_hK·h via MFMA with A = h broadcast
// to all 16 rows (D rows identical -> per-lane ownership by a cndmask tree),
// B = W_hK^T fragments resident in 128 VGPRs. No barriers anywhere: a single
// wave's LDS ops execute in issue order, so the h write(t) -> read(t+1) chain
// is naturally ordered. grid 256 blocks x 64 threads (1 wave, 1 wave/SIMD ->
// up to 512 VGPRs).
__global__ __launch_bounds__(64, 1) void fused_rnn_wave(
        const float* __restrict__ x,
        const float* __restrict__ WxK, const float* __restrict__ bxK,
        const float* __restrict__ Wxz, const float* __restrict__ bxz,
        const float* __restrict__ Whk, const float* __restrict__ bhk,
        float* __restrict__ out) {
    __shared__ __align__(16) __fp16 wsm[2][128][72];    // 36 KB: W_xK/W_xz fp16 [h][d]
    __shared__ __align__(16) __fp16 hbuf[128];          // h fp16 (single buffer: 1 wave, in-order DS)
    __shared__ __align__(16) __fp16 gbuf[2][16][132];   // gxK chunk dbuf
    __shared__ __align__(16) __fp16 zbuf[2][16][132];   // z   chunk dbuf

    const int tid = threadIdx.x;      // 0..63
    const int b = blockIdx.x;
    const int kg = tid >> 4, l16 = tid & 15;
    const int j0 = kg * 32 + l16, j1 = j0 + 16;   // this lane's two hidden units

    // ---- stage W_xK / W_xz into LDS fp16 (one-time) ----
    for (int mat = 0; mat < 2; ++mat) {
        const float* Wsrc = mat ? Wxz : WxK;
        for (int rr = 0; rr < 2; ++rr) {
            const int row = tid * 2 + rr;         // 0..127
            const float4v* ws4 = (const float4v*)(Wsrc + (size_t)row * 64);
            #pragma unroll
            for (int i = 0; i < 8; ++i) {
                float4v a = ws4[2 * i], c = ws4[2 * i + 1];
                half8 hv = {(__fp16)a.x, (__fp16)a.y, (__fp16)a.z, (__fp16)a.w,
                            (__fp16)c.x, (__fp16)c.y, (__fp16)c.z, (__fp16)c.w};
                *(half8*)&wsm[mat][row][i * 8] = hv;
            }
        }
    }
    hbuf[tid] = (__fp16)0.0f;         // h0 = 0
    hbuf[tid + 64] = (__fp16)0.0f;

    // ---- W_hK^T B-fragments resident in VGPRs (128 VGPRs) ----
    // whT[ct][kt]: B[k=kg*8+e][n=l16] = Whk[ct*16+l16][kt*32+kg*8+e]
    half8 whT[8][4];
    #pragma unroll
    for (int ct = 0; ct < 8; ++ct)
        #pragma unroll
        for (int kt = 0; kt < 4; ++kt) {
            const float* p = Whk + (size_t)(ct * 16 + l16) * 128 + kt * 32 + kg * 8;
            float4v u = *(const float4v*)p, v = *(const float4v*)(p + 4);
            whT[ct][kt] = (half8){(__fp16)u.x, (__fp16)u.y, (__fp16)u.z, (__fp16)u.w,
                                  (__fp16)v.x, (__fp16)v.y, (__fp16)v.z, (__fp16)v.w};
        }

    const float bj0 = bhk[j0], bj1 = bhk[j1];
    float bK[8], bz[8];
    #pragma unroll
    for (int ct = 0; ct < 8; ++ct) {
        bK[ct] = bxK[ct * 16 + l16];
        bz[ct] = bxz[ct * 16 + l16];
    }
    __syncthreads();   // trivial (1 wave); orders wsm/hbuf staging

    const float* xb = x + (size_t)b * NT * ND;
    float4v xf[4];     // prefetched x chunk (A-fragments, f32)

    // load x chunk c: A[row=l16][k=kt*32+kg*8+e] = x[c*16+l16][...]
    auto xload = [&](int c) {
        const float* px = xb + (size_t)c * 16 * 64 + (size_t)l16 * 64;
        #pragma unroll
        for (int kt = 0; kt < 2; ++kt) {
            const float* q = px + kt * 32 + kg * 8;
            xf[2 * kt]     = *(const float4v*)q;
            xf[2 * kt + 1] = *(const float4v*)(q + 4);
        }
    };

    // project staged chunk (in xf) into gbuf/zbuf[dst]: 32 MFMAs, once per 16 steps
    auto proj = [&](int dst) {
        half8 ax[2];
        #pragma unroll
        for (int kt = 0; kt < 2; ++kt) {
            float4v u = xf[2 * kt], v = xf[2 * kt + 1];
            ax[kt] = (half8){(__fp16)u.x, (__fp16)u.y, (__fp16)u.z, (__fp16)u.w,
                             (__fp16)v.x, (__fp16)v.y, (__fp16)v.z, (__fp16)v.w};
        }
        #pragma unroll
        for (int mat = 0; mat < 2; ++mat) {
            float4v pc[8];
            #pragma unroll
            for (int ct = 0; ct < 8; ++ct) pc[ct] = (float4v){0.f, 0.f, 0.f, 0.f};
            #pragma unroll
            for (int kt = 0; kt < 2; ++kt)
                #pragma unroll
                for (int ct = 0; ct < 8; ++ct) {
                    half8 bf = *(const half8*)&wsm[mat][ct * 16 + l16][kt * 32 + kg * 8];
                    pc[ct] = __builtin_amdgcn_mfma_f32_16x16x32_f16(ax[kt], bf, pc[ct], 0, 0, 0);
                }
            // C/D: col = lane&15, row = (lane>>4)*4 + r  (rows = timesteps of the chunk)
            #pragma unroll
            for (int ct = 0; ct < 8; ++ct) {
                const int col = ct * 16 + l16;
                #pragma unroll
                for (int r = 0; r < 4; ++r) {
                    const int row = kg * 4 + r;
                    if (mat == 0) gbuf[dst][row][col] = (__fp16)(pc[ct][r] + bK[ct]);
                    else          zbuf[dst][row][col] = (__fp16)fast_tanh(pc[ct][r] + bz[ct]);
                }
            }
        }
    };

    // ---- prologue: chunk 0 projected, chunk 1 in flight ----
    xload(0);
    proj(0);
    xload(1);

    float hn0 = 0.0f, hn1 = 0.0f;
    float oreg0[16], oreg1[16];
    const size_t CPY = (size_t)NB * NT * NH;
    float* o0 = out + (size_t)b * NT * NH;

    for (int c = 0; c < 64; ++c) {
        const int cb = c & 1;

        #pragma unroll
        for (int s = 0; s < 16; ++s) {
            // h A-fragments: broadcast read (independent of l16) — 4x ds_read_b128
            half8 ah[4];
            #pragma unroll
            for (int kt = 0; kt < 4; ++kt)
                ah[kt] = *(const half8*)&hbuf[kt * 32 + kg * 8];
            // per-step gx/z (issued early, consumed after the MFMA block)
            const float g0 = (float)gbuf[cb][s][j0];
            const float g1 = (float)gbuf[cb][s][j1];
            const float z0 = (float)zbuf[cb][s][j0];
            const float z1 = (float)zbuf[cb][s][j1];

            // y = W_hK · h : 32 MFMAs, 16 independent 2-deep chains (split K halves)
            float4v accA[8], accB[8];
            #pragma unroll
            for (int ct = 0; ct < 8; ++ct) {
                accA[ct] = (float4v){0.f, 0.f, 0.f, 0.f};
                accB[ct] = (float4v){0.f, 0.f, 0.f, 0.f};
            }
            #pragma unroll
            for (int ct = 0; ct < 8; ++ct) {
                accA[ct] = __builtin_amdgcn_mfma_f32_16x16x32_f16(ah[0], whT[ct][0], accA[ct], 0, 0, 0);
                accB[ct] = __builtin_amdgcn_mfma_f32_16x16x32_f16(ah[2], whT[ct][2], accB[ct], 0, 0, 0);
            }
            #pragma unroll
            for (int ct = 0; ct < 8; ++ct) {
                accA[ct] = __builtin_amdgcn_mfma_f32_16x16x32_f16(ah[1], whT[ct][1], accA[ct], 0, 0, 0);
                accB[ct] = __builtin_amdgcn_mfma_f32_16x16x32_f16(ah[3], whT[ct][3], accB[ct], 0, 0, 0);
            }

            // D rows identical -> reg 0; ct = 2*kg (+1) selected by cndmask tree
            const float ya0 = kg < 2 ? (kg == 0 ? accA[0][0] : accA[2][0])
                                     : (kg == 2 ? accA[4][0] : accA[6][0]);
            const float yb0 = kg < 2 ? (kg == 0 ? accB[0][0] : accB[2][0])
                                     : (kg == 2 ? accB[4][0] : accB[6][0]);
            const float ya1 = kg < 2 ? (kg == 0 ? accA[1][0] : accA[3][0])
                                     : (kg == 2 ? accA[5][0] : accA[7][0]);
            const float yb1 = kg < 2 ? (kg == 0 ? accB[1][0] : accB[3][0])
                                     : (kg == 2 ? accB[5][0] : accB[7][0]);

            // tail: K = sigmoid(y + gxK(+bias)); h = tanh(h + K*(z-h))
            const float pre0 = (ya0 + yb0) + (g0 + bj0);
            const float pre1 = (ya1 + yb1) + (g1 + bj1);
            const float K0 = __builtin_amdgcn_rcpf(1.0f + __expf(-pre0));
            const float K1 = __builtin_amdgcn_rcpf(1.0f + __expf(-pre1));
            hn0 = fast_tanh(__builtin_fmaf(K0, z0 - hn0, hn0));
            hn1 = fast_tanh(__builtin_fmaf(K1, z1 - hn1, hn1));

            hbuf[j0] = (__fp16)hn0;   // step-s reads already issued before these writes
            hbuf[j1] = (__fp16)hn1;   // (in-order per-wave DS pipe => no hazard)

            oreg0[s] = hn0;
            oreg1[s] = hn1;
        }

        // project chunk c+1 (xf loaded one chunk ago; its vmcnt wait only
        // touches VMEM that is >= 1 chunk old)
        if (c < 63) proj(cb ^ 1);

        // burst-flush this chunk's outputs (both copies)
        #pragma unroll
        for (int s = 0; s < 16; ++s) {
            float* po = o0 + (size_t)(c * 16 + s) * NH;
            po[j0] = oreg0[s];
            po[j1] = oreg1[s];
            po[CPY + j0] = oreg0[s];
            po[CPY + j1] = oreg1[s];
        }

        // prefetch x chunk c+2 (full chunk of flight time before use)
        if (c < 62) xload(c + 2);
    }
}

extern "C" void kernel_launch(void* const* d_in, const int* in_sizes, int n_in,
                              void* d_out, int out_size, void* d_ws, size_t ws_size,
                              hipStream_t stream) {
    (void)in_sizes; (void)n_in; (void)d_ws; (void)ws_size; (void)out_size;
    const float* x   = (const float*)d_in[0];
    const float* WxK = (const float*)d_in[1];
    const float* bxK = (const float*)d_in[2];
    const float* Wxz = (const float*)d_in[3];
    const float* bxz = (const float*)d_in[4];
    const float* Whk = (const float*)d_in[5];
    const float* bhk = (const float*)d_in[6];
    float* out = (float*)d_out;

    fused_rnn_wave<<<256, 64, 0, stream>>>(x, WxK, bxK, Wxz, bxz, Whk, bhk, out);
}

// Round 5
// 542.112 us; speedup vs baseline: 1.3852x; 1.3852x over previous
//
#include <hip/hip_runtime.h>
#include <hip/hip_fp16.h>

#define NB 256      // batch
#define NT 1024     // time
#define ND 64       // input dim
#define NH 128      // hidden dim

typedef __fp16 half8 __attribute__((ext_vector_type(8)));
typedef float float4v __attribute__((ext_vector_type(4)));

static __device__ __forceinline__ float fast_tanh(float v) {
    float e = __expf(2.0f * v);
    return 1.0f - 2.0f * __builtin_amdgcn_rcpf(e + 1.0f);
}

// lgkm-only barrier: does NOT drain vmcnt (stores / x prefetch keep flying)
static __device__ __forceinline__ void fast_barrier() {
    asm volatile("s_waitcnt lgkmcnt(0)\n\ts_barrier" ::: "memory");
}

// 4 waves per block (1 per SIMD), block = batch. Wave w owns hidden units
// j in [w*32, w*32+32). Per step, the matvec y = W_hK·h runs as 8 MFMAs
// (A = h broadcast to all 16 rows -> D rows identical -> every lane holds
// y[base + (lane&15)] for both ct tiles in reg 0; one cndmask selects ct).
// No cross-lane reduction, no DPP. gbuf/zbuf columns are written by the SAME
// wave that reads them (proj is barrier-free); the only sync is one
// lgkm-barrier per step for the h exchange — exactly r0's cheapest structure,
// with the dot moved off the VALU.
__global__ __launch_bounds__(256, 1) void fused_rnn_mfma(
        const float* __restrict__ x,
        const float* __restrict__ WxK, const float* __restrict__ bxK,
        const float* __restrict__ Wxz, const float* __restrict__ bxz,
        const float* __restrict__ Whk, const float* __restrict__ bhk,
        float* __restrict__ out) {
    __shared__ __align__(16) __fp16 hbuf[2][128];       // h fp16, dbuf per step parity
    __shared__ __align__(16) __fp16 gbuf[2][16][132];   // gxK+bxK+bhK chunk dbuf
    __shared__ __align__(16) __fp16 zbuf[2][16][132];   // tanh(gxz+bxz) chunk dbuf

    const int tid = threadIdx.x;
    const int b = blockIdx.x;
    const int wid = tid >> 6, lane = tid & 63;
    const int l16 = lane & 15, kg = lane >> 4;
    const int jl = lane & 31;
    const int j = wid * 32 + jl;          // this lane's hidden unit (2-lane dup)

    // ---- B-fragments resident in VGPRs ----
    // rec:  whT[ct][kt]: B[k=kg*8+e][n=l16] = Whk[wid*32+ct*16+l16][kt*32+kg*8+e]
    // proj: wxT[mat][ct][kt] same layout over Wx[.][64]
    half8 whT[2][4];
    half8 wxT[2][2][2];
    float bGK[2], bZ[2];
    #pragma unroll
    for (int ct = 0; ct < 2; ++ct) {
        const int row = wid * 32 + ct * 16 + l16;
        #pragma unroll
        for (int kt = 0; kt < 4; ++kt) {
            const float* p = Whk + (size_t)row * NH + kt * 32 + kg * 8;
            float4v u = *(const float4v*)p, v = *(const float4v*)(p + 4);
            whT[ct][kt] = (half8){(__fp16)u.x, (__fp16)u.y, (__fp16)u.z, (__fp16)u.w,
                                  (__fp16)v.x, (__fp16)v.y, (__fp16)v.z, (__fp16)v.w};
        }
        #pragma unroll
        for (int mat = 0; mat < 2; ++mat) {
            const float* W = mat ? Wxz : WxK;
            #pragma unroll
            for (int kt = 0; kt < 2; ++kt) {
                const float* p = W + (size_t)row * ND + kt * 32 + kg * 8;
                float4v u = *(const float4v*)p, v = *(const float4v*)(p + 4);
                wxT[mat][ct][kt] = (half8){(__fp16)u.x, (__fp16)u.y, (__fp16)u.z, (__fp16)u.w,
                                           (__fp16)v.x, (__fp16)v.y, (__fp16)v.z, (__fp16)v.w};
            }
        }
        bGK[ct] = bxK[row] + bhk[row];    // fold bhK into the staged gate
        bZ[ct]  = bxz[row];
    }
    const float4v zero4 = {0.f, 0.f, 0.f, 0.f};

    const float* xb = x + (size_t)b * NT * ND;
    float4v xf[4];    // prefetched x chunk A-fragments (f32)

    // load x chunk c: A[row=l16][k=kt*32+kg*8+e]
    auto xload = [&](int c) {
        const float* px = xb + (size_t)c * 16 * 64 + (size_t)l16 * 64;
        #pragma unroll
        for (int kt = 0; kt < 2; ++kt) {
            const float* q = px + kt * 32 + kg * 8;
            xf[2 * kt]     = *(const float4v*)q;
            xf[2 * kt + 1] = *(const float4v*)(q + 4);
        }
    };

    // project staged chunk into this wave's 32 columns of gbuf/zbuf[dst]:
    // 8 MFMAs + 16 fp16 writes + 8 tanh. Barrier-free (same-wave write->read).
    auto proj = [&](int dst) {
        half8 ax[2];
        #pragma unroll
        for (int kt = 0; kt < 2; ++kt) {
            float4v u = xf[2 * kt], v = xf[2 * kt + 1];
            ax[kt] = (half8){(__fp16)u.x, (__fp16)u.y, (__fp16)u.z, (__fp16)u.w,
                             (__fp16)v.x, (__fp16)v.y, (__fp16)v.z, (__fp16)v.w};
        }
        #pragma unroll
        for (int mat = 0; mat < 2; ++mat)
            #pragma unroll
            for (int ct = 0; ct < 2; ++ct) {
                float4v pc = __builtin_amdgcn_mfma_f32_16x16x32_f16(ax[0], wxT[mat][ct][0], zero4, 0, 0, 0);
                pc = __builtin_amdgcn_mfma_f32_16x16x32_f16(ax[1], wxT[mat][ct][1], pc, 0, 0, 0);
                const int col = wid * 32 + ct * 16 + l16;
                #pragma unroll
                for (int r = 0; r < 4; ++r) {
                    const int row = kg * 4 + r;
                    if (mat == 0) gbuf[dst][row][col] = (__fp16)(pc[r] + bGK[ct]);
                    else          zbuf[dst][row][col] = (__fp16)fast_tanh(pc[r] + bZ[ct]);
                }
            }
    };

    // ---- prologue ----
    xload(0);
    if (tid < 128) hbuf[0][tid] = (__fp16)0.0f;   // h0 = 0
    proj(0);                                      // chunk 0 -> buf 0
    xload(1);
    __syncthreads();                              // hbuf + (cross-check) all staging visible

    float hn = 0.0f;
    float oreg[16];
    const size_t CPY = (size_t)NB * NT * NH;
    float* ob = out + (size_t)b * NT * NH + j;

    for (int c = 0; c < 64; ++c) {
        const int cb = c & 1;

        #pragma unroll
        for (int s = 0; s < 16; ++s) {
            const int p = s & 1;                  // hbuf parity (16 steps/chunk -> stable)
            // h A-fragments: broadcast reads (addr depends only on kg) — 4x ds_read_b128
            half8 ah0 = *(const half8*)&hbuf[p][0 * 32 + kg * 8];
            half8 ah1 = *(const half8*)&hbuf[p][1 * 32 + kg * 8];
            half8 ah2 = *(const half8*)&hbuf[p][2 * 32 + kg * 8];
            half8 ah3 = *(const half8*)&hbuf[p][3 * 32 + kg * 8];
            const float gv = (float)gbuf[cb][s][j];   // includes bxK + bhK
            const float zv = (float)zbuf[cb][s][j];

            // y = W_hK·h : 8 MFMAs, 4 independent 2-deep chains
            float4v aA0 = __builtin_amdgcn_mfma_f32_16x16x32_f16(ah0, whT[0][0], zero4, 0, 0, 0);
            float4v aA1 = __builtin_amdgcn_mfma_f32_16x16x32_f16(ah0, whT[1][0], zero4, 0, 0, 0);
            float4v aB0 = __builtin_amdgcn_mfma_f32_16x16x32_f16(ah2, whT[0][2], zero4, 0, 0, 0);
            float4v aB1 = __builtin_amdgcn_mfma_f32_16x16x32_f16(ah2, whT[1][2], zero4, 0, 0, 0);
            aA0 = __builtin_amdgcn_mfma_f32_16x16x32_f16(ah1, whT[0][1], aA0, 0, 0, 0);
            aA1 = __builtin_amdgcn_mfma_f32_16x16x32_f16(ah1, whT[1][1], aA1, 0, 0, 0);
            aB0 = __builtin_amdgcn_mfma_f32_16x16x32_f16(ah3, whT[0][3], aB0, 0, 0, 0);
            aB1 = __builtin_amdgcn_mfma_f32_16x16x32_f16(ah3, whT[1][3], aB1, 0, 0, 0);

            // D rows identical -> reg 0; ct selected by lane bit 4
            const bool hi = (jl & 16) != 0;
            const float ya = hi ? aA1[0] : aA0[0];
            const float yb = hi ? aB1[0] : aB0[0];

            // tail: K = sigmoid(y + g); h = tanh(h + K*(z - h))
            const float pre = (ya + yb) + gv;
            const float K = __builtin_amdgcn_rcpf(1.0f + __expf(-pre));
            hn = fast_tanh(__builtin_fmaf(K, zv - hn, hn));
            oreg[s] = hn;

            if (lane < 32) hbuf[p ^ 1][j] = (__fp16)hn;
            fast_barrier();                       // the ONLY sync: h exchange
        }

        // burst-flush outputs (both copies); fire-and-forget VMEM
        if (lane < 32) {
            float* po = ob + (size_t)(c * 16) * NH;
            #pragma unroll
            for (int s = 0; s < 16; ++s) {
                po[(size_t)s * NH] = oreg[s];
                po[CPY + (size_t)s * NH] = oreg[s];
            }
        }

        // barrier-free proj of chunk c+1 (same-wave cols; xf loaded 1 chunk ago),
        // then prefetch x chunk c+2
        if (c < 63) {
            proj(cb ^ 1);
            if (c < 62) xload(c + 2);
        }
    }
}

extern "C" void kernel_launch(void* const* d_in, const int* in_sizes, int n_in,
                              void* d_out, int out_size, void* d_ws, size_t ws_size,
                              hipStream_t stream) {
    (void)in_sizes; (void)n_in; (void)d_ws; (void)ws_size; (void)out_size;
    const float* x   = (const float*)d_in[0];
    const float* WxK = (const float*)d_in[1];
    const float* bxK = (const float*)d_in[2];
    const float* Wxz = (const float*)d_in[3];
    const float* bxz = (const float*)d_in[4];
    const float* Whk = (const float*)d_in[5];
    const float* bhk = (const float*)d_in[6];
    float* out = (float*)d_out;

    fused_rnn_mfma<<<256, 256, 0, stream>>>(x, WxK, bxK, Wxz, bxz, Whk, bhk, out);
}